// Round 16
// baseline (271.161 us; speedup 1.0000x reference)
//
#include <hip/hip_runtime.h>
#include <cstddef>

#define SLOPE 0.01f
#define BN_EPS 1e-5f

typedef __attribute__((ext_vector_type(8))) short short8;
typedef __attribute__((ext_vector_type(4))) float floatx4;

__device__ __forceinline__ float lrelu(float t) { return fmaxf(t, SLOPE * t); }

__device__ __forceinline__ unsigned short f2bf(float f) {
    union { float f; unsigned int u; } x; x.f = f;
    unsigned int r = (x.u + 0x7fff + ((x.u >> 16) & 1)) >> 16;   // RNE
    return (unsigned short)r;
}
__device__ __forceinline__ float bf2f(unsigned short h) {
    union { unsigned int u; float f; } x; x.u = ((unsigned int)h) << 16;
    return x.f;
}

// BN affine for channel c from raw sums. st: [sum(256) | sumsq(256)].
__device__ __forceinline__ void bn_coeff(const float* __restrict__ st,
                                         const float* __restrict__ g,
                                         const float* __restrict__ be,
                                         float invN, int c, float& sc, float& sh) {
    float m   = st[c] * invN;
    float var = fmaf(st[256 + c], invN, -m * m);
    float r   = rsqrtf(var + BN_EPS);
    sc = g[c] * r;
    sh = fmaf(-sc, m, be[c]);
}

// ---------------------------------------------------------------------------
// Weight reorder (all 4 MFMA layers): w[co][ci][t] fp32 -> Wr[t][co][ci_pad].
// ---------------------------------------------------------------------------
__device__ __forceinline__ void reorder1(const float* __restrict__ w,
                                         unsigned short* __restrict__ wr,
                                         int Cout, int Cinpad, int Cin, int id) {
    int ci = id % Cinpad;
    int rest = id / Cinpad;
    int co = rest % Cout;
    int t  = rest / Cout;
    float v = (ci < Cin) ? w[((size_t)co * Cin + ci) * 3 + t] : 0.0f;
    wr[id] = f2bf(v);
}

__global__ __launch_bounds__(256) void prepw_all_kernel(
    const float* __restrict__ w1, unsigned short* __restrict__ o1,
    const float* __restrict__ w2, unsigned short* __restrict__ o2,
    const float* __restrict__ w3, unsigned short* __restrict__ o3,
    const float* __restrict__ w4, unsigned short* __restrict__ o4)
{
    int id = blockIdx.x * 256 + threadIdx.x;
    const int n1 = 3 * 128 * 64;
    const int n2 = 3 * 256 * 128;
    const int n3 = 3 * 128 * 160;
    const int n4 = 3 * 128 * 192;
    if (id < n1) { reorder1(w1, o1, 128, 64, 64, id); return; }
    id -= n1;
    if (id < n2) { reorder1(w2, o2, 256, 128, 128, id); return; }
    id -= n2;
    if (id < n3) { reorder1(w3, o3, 128, 160, 139, id); return; }
    id -= n3;
    if (id < n4) { reorder1(w4, o4, 128, 192, 192, id); return; }
}

// ---------------------------------------------------------------------------
// enc0: (B,1,16384) -> raw bf16 f0 [b][8192][64] + stats.
// ---------------------------------------------------------------------------
__global__ __launch_bounds__(256) void enc0_kernel(
    const float* __restrict__ x, const float* __restrict__ w,
    const float* __restrict__ bias, unsigned short* __restrict__ f0,
    float* __restrict__ st)
{
    __shared__ float ssum[64], ssq[64];
    const int tid = threadIdx.x;
    const int co  = tid & 63;
    const int b   = blockIdx.z;
    if (tid < 64) { ssum[tid] = 0.f; ssq[tid] = 0.f; }
    __syncthreads();
    const float w0 = w[co * 3], w1 = w[co * 3 + 1], w2 = w[co * 3 + 2];
    const float bs = bias[co];
    const float* xb = x + (size_t)b * 16384;
    float lsum = 0.f, lsq = 0.f;
    const int obase = blockIdx.x * 128 + (tid >> 6) * 32;
    for (int k = 0; k < 32; ++k) {
        int o = obase + k;
        int xi = 2 * o - 1;
        float x0v = (xi >= 0) ? xb[xi] : 0.f;
        float a = bs;
        a = fmaf(w0, x0v, a);
        a = fmaf(w1, xb[xi + 1], a);
        a = fmaf(w2, xb[xi + 2], a);
        f0[((size_t)(b * 8192 + o)) * 64 + co] = f2bf(a);
        lsum += a; lsq = fmaf(a, a, lsq);
    }
    atomicAdd(&ssum[co], lsum);
    atomicAdd(&ssq[co], lsq);
    __syncthreads();
    if (tid < 64) {
        atomicAdd(&st[tid],       ssum[tid]);
        atomicAdd(&st[256 + tid], ssq[tid]);
    }
}

// ---------------------------------------------------------------------------
// MFMA implicit-GEMM conv, channel-last bf16, DEPTH-2 register pipeline:
// iter ch: issue ch+2 global loads (regs, fixed-trip) -> MFMA(ch) from LDS
// -> publish ch+1 regs (norm + ds_write; vmcnt wait covered by TWO MFMA
// blocks) -> one barrier. Two reg sets alternate by compile-time parity.
// x/w LDS double-buffered, 36-short padded rows. Padding rows stay zero.
// M-tile = 128 pos x 64 co. Grid: (L_out/128, Cout/64, B).
// ---------------------------------------------------------------------------
template<int STRIDE>
__global__ __launch_bounds__(256) void conv_mfma_kernel(
    const unsigned short* __restrict__ xA, int CAc,
    const float* __restrict__ stA, const float* __restrict__ gA,
    const float* __restrict__ beA, float invNA,
    const unsigned short* __restrict__ xB, int CBc,
    const float* __restrict__ stB, const float* __restrict__ gB,
    const float* __restrict__ beB, float invNB,
    const unsigned short* __restrict__ Wr, const float* __restrict__ bias,
    unsigned short* __restrict__ out, int L_in, int L_out, int Cout,
    float* __restrict__ st)
{
    constexpr int SEG  = 127 * STRIDE + 3;
    constexpr int XPC  = (SEG * 4 + 255) / 256;
    constexpr int XPAD = 36;
    __shared__ __align__(16) unsigned short x_tile[2][SEG * XPAD];
    __shared__ __align__(16) unsigned short w_tile[2][3 * 64 * XPAD];
    __shared__ float ssum[64], ssq[64];
    __shared__ float csc[192], csh[192];

    const int tid  = threadIdx.x;
    const int wv   = tid >> 6;
    const int lane = tid & 63;
    const int col  = lane & 15;
    const int quad = lane >> 4;
    const int oblk = blockIdx.x * 128;
    const int cob  = blockIdx.y * 64;
    const int b    = blockIdx.z;
    const int nch    = CAc + CBc;
    const int CApad  = CAc * 32;
    const int CBpad  = CBc * 32;
    const int Cinpad = nch * 32;
    const int LB     = L_in >> 1;
    const bool nA = (stA != nullptr);
    const bool nB = (stB != nullptr);

    if (tid < 64) { ssum[tid] = 0.f; ssq[tid] = 0.f; }
    for (int c = tid; c < Cinpad; c += 256) {
        float sc = 1.f, sh = 0.f;
        if (c < CApad) { if (nA) bn_coeff(stA, gA, beA, invNA, c, sc, sh); }
        else           { if (nB) bn_coeff(stB, gB, beB, invNB, c - CApad, sc, sh); }
        csc[c] = sc; csh[c] = sh;
    }

    floatx4 acc[2][4];
    #pragma unroll
    for (int ps = 0; ps < 2; ++ps)
        #pragma unroll
        for (int s = 0; s < 4; ++s)
            acc[ps][s] = (floatx4){0.f, 0.f, 0.f, 0.f};

    const int x0 = oblk * STRIDE - 1;

    short8 xrE[XPC], xrO[XPC];
    short8 wrE[3],  wrO[3];

    // issue global loads for chunk ch into the given register sets (no wait)
    auto issue = [&](int ch, short8 (&xr)[XPC], short8 (&wr)[3]) {
        #pragma unroll
        for (int k = 0; k < XPC; ++k) {
            const int r = tid + k * 256;
            short8 v = {0, 0, 0, 0, 0, 0, 0, 0};
            if (r < SEG * 4) {
                const int pi = r >> 2, part = r & 3;
                const int gp = x0 + pi;
                if (gp >= 0 && gp < L_in) {
                    if (ch < CAc)
                        v = *(const short8*)(xA + ((size_t)b * L_in + gp) * CApad + ch * 32 + part * 8);
                    else
                        v = *(const short8*)(xB + ((size_t)b * LB + (gp >> 1)) * CBpad + (ch - CAc) * 32 + part * 8);
                }
            }
            xr[k] = v;
        }
        #pragma unroll
        for (int k = 0; k < 3; ++k) {     // 768 = 3*256 exactly
            const int r = tid + k * 256;
            const int part = r & 3;
            const int co   = (r >> 2) & 63;
            const int t    = r >> 8;
            wr[k] = *(const short8*)(Wr + ((size_t)(t * Cout + cob + co)) * Cinpad + ch * 32 + part * 8);
        }
    };

    // normalize (in-range rows only) + publish regs to LDS buffer ch&1
    auto publish = [&](int ch, short8 (&xr)[XPC], short8 (&wr)[3]) {
        const int buf = ch & 1;
        const bool applyN = (ch < CAc) ? nA : nB;
        #pragma unroll
        for (int k = 0; k < XPC; ++k) {
            const int r = tid + k * 256;
            if (r < SEG * 4) {
                const int pi = r >> 2, part = r & 3;
                const int gp = x0 + pi;
                short8 v = xr[k];
                if (applyN && gp >= 0 && gp < L_in) {
                    const int cb = ch * 32 + part * 8;
                    #pragma unroll
                    for (int e = 0; e < 8; ++e) {
                        float f = bf2f((unsigned short)v[e]);
                        f = lrelu(fmaf(f, csc[cb + e], csh[cb + e]));
                        v[e] = (short)f2bf(f);
                    }
                }
                *(short8*)(x_tile[buf] + pi * XPAD + part * 8) = v;
            }
        }
        #pragma unroll
        for (int k = 0; k < 3; ++k) {
            const int r = tid + k * 256;
            const int part = r & 3;
            const int co   = (r >> 2) & 63;
            const int t    = r >> 8;
            *(short8*)(w_tile[buf] + (t * 64 + co) * XPAD + part * 8) = wr[k];
        }
    };

    auto mfma_step = [&](int ch) {
        const int cur = ch & 1;
        #pragma unroll
        for (int t = 0; t < 3; ++t) {
            short8 bfr[4];
            #pragma unroll
            for (int s = 0; s < 4; ++s)
                bfr[s] = *(const short8*)(w_tile[cur] + (t * 64 + s * 16 + col) * XPAD + quad * 8);
            #pragma unroll
            for (int ps = 0; ps < 2; ++ps) {
                const int xi = (wv * 32 + ps * 16 + col) * STRIDE + t;
                short8 afr = *(const short8*)(x_tile[cur] + xi * XPAD + quad * 8);
                #pragma unroll
                for (int s = 0; s < 4; ++s)
                    acc[ps][s] = __builtin_amdgcn_mfma_f32_16x16x32_bf16(afr, bfr[s], acc[ps][s], 0, 0, 0);
            }
        }
    };

    // prologue: loads for chunks 0 and 1 in flight before anything else
    issue(0, xrE, wrE);
    if (nch > 1) issue(1, xrO, wrO);
    __syncthreads();        // csc/csh + stats init visible (issue reads no LDS)
    publish(0, xrE, wrE);
    __syncthreads();        // buf0 ready

    for (int ch = 0; ch < nch; ++ch) {
        if ((ch & 1) == 0) {
            if (ch + 2 < nch) issue(ch + 2, xrE, wrE);   // set freed by publish(ch)
            mfma_step(ch);
            if (ch + 1 < nch) publish(ch + 1, xrO, wrO); // vmcnt covered 2 iters
        } else {
            if (ch + 2 < nch) issue(ch + 2, xrO, wrO);
            mfma_step(ch);
            if (ch + 1 < nch) publish(ch + 1, xrE, wrE);
        }
        __syncthreads();
    }

    float bv[4];
    #pragma unroll
    for (int s = 0; s < 4; ++s) bv[s] = bias[cob + s * 16 + col];
    #pragma unroll
    for (int ps = 0; ps < 2; ++ps)
        #pragma unroll
        for (int s = 0; s < 4; ++s)
            #pragma unroll
            for (int r = 0; r < 4; ++r)
                acc[ps][s][r] += bv[s];

    #pragma unroll
    for (int ps = 0; ps < 2; ++ps) {
        const int pos0 = oblk + wv * 32 + ps * 16 + quad * 4;
        #pragma unroll
        for (int s = 0; s < 4; ++s) {
            unsigned short* op = out + ((size_t)b * L_out + pos0) * Cout + cob + s * 16 + col;
            #pragma unroll
            for (int r = 0; r < 4; ++r)
                op[(size_t)r * Cout] = f2bf(acc[ps][s][r]);
        }
    }

    #pragma unroll
    for (int s = 0; s < 4; ++s) {
        float v = 0.f, q = 0.f;
        #pragma unroll
        for (int ps = 0; ps < 2; ++ps)
            #pragma unroll
            for (int r = 0; r < 4; ++r) {
                float a = acc[ps][s][r];
                v += a; q = fmaf(a, a, q);
            }
        v += __shfl_xor(v, 16); v += __shfl_xor(v, 32);
        q += __shfl_xor(q, 16); q += __shfl_xor(q, 32);
        if (quad == 0) {
            atomicAdd(&ssum[s * 16 + col], v);
            atomicAdd(&ssq[s * 16 + col],  q);
        }
    }
    __syncthreads();
    if (tid < 64) {
        atomicAdd(&st[cob + tid],       ssum[tid]);
        atomicAdd(&st[256 + cob + tid], ssq[tid]);
    }
}

// ---------------------------------------------------------------------------
// Banded correlation fusion on RAW f2 (BN+lrelu at staging). Block = 32
// positions x 1 batch (512 blocks); thread = (pos, 32-ch eighth).
// ---------------------------------------------------------------------------
__global__ __launch_bounds__(256) void fusion_kernel(
    const unsigned short* __restrict__ f2,
    const float* __restrict__ st, const float* __restrict__ g,
    const float* __restrict__ be, float invN,
    unsigned short* __restrict__ feat)
{
    constexpr int ROWS = 44;
    constexpr int CPAD = 272;
    __shared__ __align__(16) unsigned short tile[ROWS * CPAD];
    __shared__ float csc[256], csh[256];
    const int tid = threadIdx.x;
    const int p0  = blockIdx.x * 32;
    const int b   = blockIdx.y;
    const unsigned short* base = f2 + (size_t)b * 2048 * 256;

    {
        float sc, sh;
        bn_coeff(st, g, be, invN, tid, sc, sh);
        csc[tid] = sc; csh[tid] = sh;
    }
    __syncthreads();
    float scr[8], shr[8];
    {
        const int cb = (tid & 31) * 8;
        #pragma unroll
        for (int e = 0; e < 8; ++e) { scr[e] = csc[cb + e]; shr[e] = csh[cb + e]; }
    }
    for (int r = tid; r < ROWS * 32; r += 256) {
        int row = r >> 5, piece = r & 31;
        int grow = min(max(p0 - 6 + row, 0), 2047);
        short8 v = *(const short8*)(base + (size_t)grow * 256 + piece * 8);
        #pragma unroll
        for (int e = 0; e < 8; ++e) {
            float f = bf2f((unsigned short)v[e]);
            f = lrelu(fmaf(f, scr[e], shr[e]));
            v[e] = (short)f2bf(f);
        }
        *(short8*)(tile + row * CPAD + piece * 8) = v;
    }
    __syncthreads();

    const int il = tid >> 3;
    const int q  = tid & 7;
    const int i  = p0 + il;

    float acc[11];
    #pragma unroll
    for (int d = 0; d < 11; ++d) acc[d] = 0.f;

    int ra[3];
    #pragma unroll
    for (int j = 0; j < 3; ++j)
        ra[j] = (min(max(i + j - 1, 0), 2047) - p0 + 6) * CPAD;
    int rb[11][3];
    #pragma unroll
    for (int d = 0; d < 11; ++d) {
        int i2 = min(max(i + d - 5, 0), 2047);
        #pragma unroll
        for (int j = 0; j < 3; ++j)
            rb[d][j] = (min(max(i2 + j - 1, 0), 2047) - p0 + 6) * CPAD;
    }

    for (int ck = 0; ck < 4; ++ck) {
        const int coff = q * 32 + ck * 8;
        float fa[3][8];
        #pragma unroll
        for (int j = 0; j < 3; ++j) {
            short8 v = *(const short8*)(tile + ra[j] + coff);
            #pragma unroll
            for (int e = 0; e < 8; ++e) fa[j][e] = bf2f((unsigned short)v[e]);
        }
        #pragma unroll
        for (int d = 0; d < 11; ++d) {
            #pragma unroll
            for (int j = 0; j < 3; ++j) {
                short8 v = *(const short8*)(tile + rb[d][j] + coff);
                #pragma unroll
                for (int e = 0; e < 8; ++e)
                    acc[d] = fmaf(fa[j][e], bf2f((unsigned short)v[e]), acc[d]);
            }
        }
    }

    #pragma unroll
    for (int d = 0; d < 11; ++d) {
        acc[d] += __shfl_xor(acc[d], 1);
        acc[d] += __shfl_xor(acc[d], 2);
        acc[d] += __shfl_xor(acc[d], 4);
    }
    if (q == 0) {
        unsigned short* op = feat + ((size_t)(b * 2048 + i)) * 32;
        #pragma unroll
        for (int d = 0; d < 11; ++d) op[d] = f2bf(acc[d]);
        #pragma unroll
        for (int d = 11; d < 32; ++d) op[d] = 0;
    }
}

// ---------------------------------------------------------------------------
// Flow head (K=1, Cout=2) on raw d0 (BN+lrelu inline) + stats.
// ---------------------------------------------------------------------------
__global__ __launch_bounds__(256) void flow_kernel(
    const float* __restrict__ scan1, const unsigned short* __restrict__ d0,
    const float* __restrict__ st4, const float* __restrict__ g4,
    const float* __restrict__ be4, float invN4,
    const float* __restrict__ fw, const float* __restrict__ fb,
    float* __restrict__ outr, float* __restrict__ st)
{
    __shared__ float s4[4][4];
    __shared__ float csc[128], csh[128];
    const int tid = threadIdx.x;
    const int b = blockIdx.z;
    const int i = blockIdx.x * 256 + tid;
    if (tid < 128) {
        float sc, sh;
        bn_coeff(st4, g4, be4, invN4, tid, sc, sh);
        csc[tid] = sc; csh[tid] = sh;
    }
    __syncthreads();
    float sv = scan1[(size_t)b * 16384 + i];
    const unsigned short* row = d0 + ((size_t)(b * 8192 + (i >> 1))) * 128;
    float a0 = fmaf(fw[0],   sv, fb[0]);
    float a1 = fmaf(fw[129], sv, fb[1]);
    for (int c8 = 0; c8 < 16; ++c8) {
        short8 v = *(const short8*)(row + c8 * 8);
        #pragma unroll
        for (int j = 0; j < 8; ++j) {
            int cc = c8 * 8 + j;
            float f = bf2f((unsigned short)v[j]);
            f = lrelu(fmaf(f, csc[cc], csh[cc]));
            a0 = fmaf(fw[1 + cc],   f, a0);
            a1 = fmaf(fw[130 + cc], f, a1);
        }
    }
    float2 o; o.x = a0; o.y = a1;
    *(float2*)(outr + ((size_t)(b * 16384 + i)) * 2) = o;
    float s0 = a0, q0 = a0 * a0, s1 = a1, q1 = a1 * a1;
    #pragma unroll
    for (int off = 1; off < 64; off <<= 1) {
        s0 += __shfl_xor(s0, off); q0 += __shfl_xor(q0, off);
        s1 += __shfl_xor(s1, off); q1 += __shfl_xor(q1, off);
    }
    if ((tid & 63) == 0) {
        int w = tid >> 6;
        s4[w][0] = s0; s4[w][1] = q0; s4[w][2] = s1; s4[w][3] = q1;
    }
    __syncthreads();
    if (tid == 0) {
        float t0 = 0, t1 = 0, t2 = 0, t3 = 0;
        for (int w = 0; w < 4; ++w) {
            t0 += s4[w][0]; t1 += s4[w][1]; t2 += s4[w][2]; t3 += s4[w][3];
        }
        atomicAdd(&st[0],   t0); atomicAdd(&st[256],     t1);
        atomicAdd(&st[1],   t2); atomicAdd(&st[256 + 1], t3);
    }
}

// Final: BN + lrelu on flow raw -> d_out (B,N,2) fp32.
__global__ __launch_bounds__(256) void final_kernel(
    const float* __restrict__ raw, const float* __restrict__ st,
    const float* __restrict__ g, const float* __restrict__ be,
    float invN, float* __restrict__ out)
{
    int idx = blockIdx.x * 256 + threadIdx.x;
    float sc0, sh0, sc1, sh1;
    bn_coeff(st, g, be, invN, 0, sc0, sh0);
    bn_coeff(st, g, be, invN, 1, sc1, sh1);
    float2 v = *(const float2*)(raw + (size_t)idx * 2);
    float2 o;
    o.x = lrelu(fmaf(v.x, sc0, sh0));
    o.y = lrelu(fmaf(v.y, sc1, sh1));
    *(float2*)(out + (size_t)idx * 2) = o;
}

// ---------------------------------------------------------------------------

extern "C" void kernel_launch(void* const* d_in, const int* in_sizes, int n_in,
                              void* d_out, int out_size, void* d_ws, size_t ws_size,
                              hipStream_t stream)
{
    const int B = 8;
    const float* scan1 = (const float*)d_in[0];
    const float* enc0_w = (const float*)d_in[1];
    const float* enc0_b = (const float*)d_in[2];
    const float* enc0_g = (const float*)d_in[3];
    const float* enc0_be= (const float*)d_in[4];
    const float* enc1_w = (const float*)d_in[5];
    const float* enc1_b = (const float*)d_in[6];
    const float* enc1_g = (const float*)d_in[7];
    const float* enc1_be= (const float*)d_in[8];
    const float* enc2_w = (const float*)d_in[9];
    const float* enc2_b = (const float*)d_in[10];
    const float* enc2_g = (const float*)d_in[11];
    const float* enc2_be= (const float*)d_in[12];
    const float* dec1_w = (const float*)d_in[13];
    const float* dec1_b = (const float*)d_in[14];
    const float* dec1_g = (const float*)d_in[15];
    const float* dec1_be= (const float*)d_in[16];
    const float* dec0_w = (const float*)d_in[17];
    const float* dec0_b = (const float*)d_in[18];
    const float* dec0_g = (const float*)d_in[19];
    const float* dec0_be= (const float*)d_in[20];
    const float* flow_w = (const float*)d_in[21];
    const float* flow_b = (const float*)d_in[22];
    const float* flow_g = (const float*)d_in[23];
    const float* flow_be= (const float*)d_in[24];

    char* ws = (char*)d_ws;
    unsigned short* f0    = (unsigned short*)(ws);             // [8][8192][64] raw
    unsigned short* f1    = (unsigned short*)(ws + 8388608);   // [8][4096][128] raw
    unsigned short* f2    = (unsigned short*)(ws + 16777216);  // [8][2048][256] raw
    unsigned short* featn = (unsigned short*)(ws + 25165824);  // [8][2048][32]
    unsigned short* d1    = (unsigned short*)(ws + 26214400);  // [8][4096][128] raw
    unsigned short* d0    = (unsigned short*)(ws + 34603008);  // [8][8192][128] raw
    float*  flow_r = (float*)(ws + 51380224);                  // [8][16384][2]
    unsigned short* wr1 = (unsigned short*)(ws + 52428800);    // [3][128][64]
    unsigned short* wr2 = (unsigned short*)(ws + 52477952);    // [3][256][128]
    unsigned short* wr3 = (unsigned short*)(ws + 52674560);    // [3][128][160]
    unsigned short* wr4 = (unsigned short*)(ws + 52797440);    // [3][128][192]
    float* st = (float*)(ws + 52944896);                       // 6 x 512 floats
    float* st0 = st, *st1 = st + 512, *st2 = st + 1024;
    float* st3 = st + 1536, *st4 = st + 2048, *st5 = st + 2560;

    const float iN0 = 1.0f / (B * 8192.0f);
    const float iN1 = 1.0f / (B * 4096.0f);
    const float iN2 = 1.0f / (B * 2048.0f);
    const float iN3 = 1.0f / (B * 4096.0f);
    const float iN4 = 1.0f / (B * 8192.0f);
    const float iN5 = 1.0f / (B * 16384.0f);

    hipMemsetAsync(st, 0, 6 * 512 * sizeof(float), stream);

    prepw_all_kernel<<<1008, 256, 0, stream>>>(enc1_w, wr1, enc2_w, wr2,
                                               dec1_w, wr3, dec0_w, wr4);

    // enc0 (VALU): scan1 -> f0 raw + st0
    enc0_kernel<<<dim3(64, 1, B), 256, 0, stream>>>(scan1, enc0_w, enc0_b, f0, st0);

    // enc1 (MFMA, stride 2): norm(f0; st0) -> f1 raw + st1
    conv_mfma_kernel<2><<<dim3(32, 2, B), 256, 0, stream>>>(
        f0, 2, st0, enc0_g, enc0_be, iN0,
        nullptr, 0, nullptr, nullptr, nullptr, 0.f,
        wr1, enc1_b, f1, 8192, 4096, 128, st1);

    // enc2 (MFMA, stride 2): norm(f1; st1) -> f2 raw + st2
    conv_mfma_kernel<2><<<dim3(16, 4, B), 256, 0, stream>>>(
        f1, 4, st1, enc1_g, enc1_be, iN1,
        nullptr, 0, nullptr, nullptr, nullptr, 0.f,
        wr2, enc2_b, f2, 4096, 2048, 256, st2);

    // fusion: banded correlation on norm(f2; st2)
    fusion_kernel<<<dim3(64, B), 256, 0, stream>>>(f2, st2, enc2_g, enc2_be, iN2, featn);

    // dec1 (MFMA, stride 1): concat(norm(f1; st1), up2(featn raw)) -> d1 raw + st3
    conv_mfma_kernel<1><<<dim3(32, 2, B), 256, 0, stream>>>(
        f1, 4, st1, enc1_g, enc1_be, iN1,
        featn, 1, nullptr, nullptr, nullptr, 0.f,
        wr3, dec1_b, d1, 4096, 4096, 128, st3);

    // dec0 (MFMA, stride 1): concat(norm(f0; st0), up2(norm(d1; st3))) -> d0 raw + st4
    conv_mfma_kernel<1><<<dim3(64, 2, B), 256, 0, stream>>>(
        f0, 2, st0, enc0_g, enc0_be, iN0,
        d1, 4, st3, dec1_g, dec1_be, iN3,
        wr4, dec0_b, d0, 8192, 8192, 128, st4);

    // flow head (VALU): concat(scan1, up2(norm(d0; st4))) -> flow_r + st5
    flow_kernel<<<dim3(64, 1, B), 256, 0, stream>>>(
        scan1, d0, st4, dec0_g, dec0_be, iN4, flow_w, flow_b, flow_r, st5);

    // final BN + lrelu -> d_out
    final_kernel<<<512, 256, 0, stream>>>(flow_r, st5, flow_g, flow_be, iN5, (float*)d_out);
}

// Round 17
// 246.322 us; speedup vs baseline: 1.1008x; 1.1008x over previous
//
#include <hip/hip_runtime.h>
#include <cstddef>

#define SLOPE 0.01f
#define BN_EPS 1e-5f

typedef __attribute__((ext_vector_type(8))) short short8;
typedef __attribute__((ext_vector_type(4))) float floatx4;

__device__ __forceinline__ float lrelu(float t) { return fmaxf(t, SLOPE * t); }

__device__ __forceinline__ unsigned short f2bf(float f) {
    union { float f; unsigned int u; } x; x.f = f;
    unsigned int r = (x.u + 0x7fff + ((x.u >> 16) & 1)) >> 16;   // RNE
    return (unsigned short)r;
}
__device__ __forceinline__ float bf2f(unsigned short h) {
    union { unsigned int u; float f; } x; x.u = ((unsigned int)h) << 16;
    return x.f;
}

// BN affine for channel c from raw sums. st: [sum(256) | sumsq(256)].
__device__ __forceinline__ void bn_coeff(const float* __restrict__ st,
                                         const float* __restrict__ g,
                                         const float* __restrict__ be,
                                         float invN, int c, float& sc, float& sh) {
    float m   = st[c] * invN;
    float var = fmaf(st[256 + c], invN, -m * m);
    float r   = rsqrtf(var + BN_EPS);
    sc = g[c] * r;
    sh = fmaf(-sc, m, be[c]);
}

// ---------------------------------------------------------------------------
// Fused: enc0 conv (blocks 0..511) + weight reorder for all 4 MFMA layers
// (blocks 512..1519). Independent work; prepw outputs first consumed by the
// NEXT dispatch (enc1). Saves one launch.
// ---------------------------------------------------------------------------
__device__ __forceinline__ void reorder1(const float* __restrict__ w,
                                         unsigned short* __restrict__ wr,
                                         int Cout, int Cinpad, int Cin, int id) {
    int ci = id % Cinpad;
    int rest = id / Cinpad;
    int co = rest % Cout;
    int t  = rest / Cout;
    float v = (ci < Cin) ? w[((size_t)co * Cin + ci) * 3 + t] : 0.0f;
    wr[id] = f2bf(v);
}

__global__ __launch_bounds__(256) void enc0_prepw_kernel(
    const float* __restrict__ x, const float* __restrict__ w,
    const float* __restrict__ bias, unsigned short* __restrict__ f0,
    float* __restrict__ st,
    const float* __restrict__ w1, unsigned short* __restrict__ o1,
    const float* __restrict__ w2, unsigned short* __restrict__ o2,
    const float* __restrict__ w3, unsigned short* __restrict__ o3,
    const float* __restrict__ w4, unsigned short* __restrict__ o4)
{
    const int tid = threadIdx.x;
    const int bx  = blockIdx.x;

    if (bx >= 512) {                    // ---- weight reorder part ----
        int id = (bx - 512) * 256 + tid;
        const int n1 = 3 * 128 * 64;
        const int n2 = 3 * 256 * 128;
        const int n3 = 3 * 128 * 160;
        const int n4 = 3 * 128 * 192;
        if (id < n1) { reorder1(w1, o1, 128, 64, 64, id); return; }
        id -= n1;
        if (id < n2) { reorder1(w2, o2, 256, 128, 128, id); return; }
        id -= n2;
        if (id < n3) { reorder1(w3, o3, 128, 160, 139, id); return; }
        id -= n3;
        if (id < n4) { reorder1(w4, o4, 128, 192, 192, id); return; }
        return;
    }

    // ---- enc0 part: (B,1,16384) -> raw bf16 f0 [b][8192][64] + stats ----
    __shared__ float ssum[64], ssq[64];
    const int co = tid & 63;
    const int b  = bx >> 6;
    const int xb = bx & 63;
    if (tid < 64) { ssum[tid] = 0.f; ssq[tid] = 0.f; }
    __syncthreads();
    const float w0 = w[co * 3], w1c = w[co * 3 + 1], w2c = w[co * 3 + 2];
    const float bs = bias[co];
    const float* xbp = x + (size_t)b * 16384;
    float lsum = 0.f, lsq = 0.f;
    const int obase = xb * 128 + (tid >> 6) * 32;
    for (int k = 0; k < 32; ++k) {
        int o = obase + k;
        int xi = 2 * o - 1;
        float x0v = (xi >= 0) ? xbp[xi] : 0.f;
        float a = bs;
        a = fmaf(w0, x0v, a);
        a = fmaf(w1c, xbp[xi + 1], a);
        a = fmaf(w2c, xbp[xi + 2], a);
        f0[((size_t)(b * 8192 + o)) * 64 + co] = f2bf(a);
        lsum += a; lsq = fmaf(a, a, lsq);
    }
    atomicAdd(&ssum[co], lsum);
    atomicAdd(&ssq[co], lsq);
    __syncthreads();
    if (tid < 64) {
        atomicAdd(&st[tid],       ssum[tid]);
        atomicAdd(&st[256 + tid], ssq[tid]);
    }
}

// ---------------------------------------------------------------------------
// MFMA implicit-GEMM conv, channel-last bf16, depth-1 register pipeline
// (R15 — measured best): per chunk: (1) issue ch+1 global loads into
// FIXED-TRIP unrolled register arrays; (2) MFMA(ch) from LDS; (3) norm +
// ds_write regs into other buffer (vmcnt wait after MFMA); (4) one barrier.
// x/w tiles double-buffered, 36-short padded rows (conflict-free b128).
// Padding rows stay zero. M-tile = 128 pos x 64 co.
// Grid: (L_out/128, Cout/64, B).
// ---------------------------------------------------------------------------
template<int STRIDE>
__global__ __launch_bounds__(256) void conv_mfma_kernel(
    const unsigned short* __restrict__ xA, int CAc,
    const float* __restrict__ stA, const float* __restrict__ gA,
    const float* __restrict__ beA, float invNA,
    const unsigned short* __restrict__ xB, int CBc,
    const float* __restrict__ stB, const float* __restrict__ gB,
    const float* __restrict__ beB, float invNB,
    const unsigned short* __restrict__ Wr, const float* __restrict__ bias,
    unsigned short* __restrict__ out, int L_in, int L_out, int Cout,
    float* __restrict__ st)
{
    constexpr int SEG  = 127 * STRIDE + 3;
    constexpr int XPC  = (SEG * 4 + 255) / 256;
    constexpr int XPAD = 36;
    __shared__ __align__(16) unsigned short x_tile[2][SEG * XPAD];
    __shared__ __align__(16) unsigned short w_tile[2][3 * 64 * XPAD];
    __shared__ float ssum[64], ssq[64];
    __shared__ float csc[192], csh[192];

    const int tid  = threadIdx.x;
    const int wv   = tid >> 6;
    const int lane = tid & 63;
    const int col  = lane & 15;
    const int quad = lane >> 4;
    const int oblk = blockIdx.x * 128;
    const int cob  = blockIdx.y * 64;
    const int b    = blockIdx.z;
    const int nch    = CAc + CBc;
    const int CApad  = CAc * 32;
    const int CBpad  = CBc * 32;
    const int Cinpad = nch * 32;
    const int LB     = L_in >> 1;
    const bool nA = (stA != nullptr);
    const bool nB = (stB != nullptr);

    if (tid < 64) { ssum[tid] = 0.f; ssq[tid] = 0.f; }
    for (int c = tid; c < Cinpad; c += 256) {
        float sc = 1.f, sh = 0.f;
        if (c < CApad) { if (nA) bn_coeff(stA, gA, beA, invNA, c, sc, sh); }
        else           { if (nB) bn_coeff(stB, gB, beB, invNB, c - CApad, sc, sh); }
        csc[c] = sc; csh[c] = sh;
    }

    floatx4 acc[2][4];
    #pragma unroll
    for (int ps = 0; ps < 2; ++ps)
        #pragma unroll
        for (int s = 0; s < 4; ++s)
            acc[ps][s] = (floatx4){0.f, 0.f, 0.f, 0.f};

    const int x0 = oblk * STRIDE - 1;

    short8 xr[XPC];
    short8 wr3[3];

    // issue global loads for chunk ch into registers (fixed trips, no wait)
    auto load_regs = [&](int ch) {
        #pragma unroll
        for (int k = 0; k < XPC; ++k) {
            const int r = tid + k * 256;
            short8 v = {0, 0, 0, 0, 0, 0, 0, 0};
            if (r < SEG * 4) {
                const int pi = r >> 2, part = r & 3;
                const int gp = x0 + pi;
                if (gp >= 0 && gp < L_in) {
                    if (ch < CAc)
                        v = *(const short8*)(xA + ((size_t)b * L_in + gp) * CApad + ch * 32 + part * 8);
                    else
                        v = *(const short8*)(xB + ((size_t)b * LB + (gp >> 1)) * CBpad + (ch - CAc) * 32 + part * 8);
                }
            }
            xr[k] = v;
        }
        #pragma unroll
        for (int k = 0; k < 3; ++k) {     // 768 = 3*256 exactly
            const int r = tid + k * 256;
            const int part = r & 3;
            const int co   = (r >> 2) & 63;
            const int t    = r >> 8;
            wr3[k] = *(const short8*)(Wr + ((size_t)(t * Cout + cob + co)) * Cinpad + ch * 32 + part * 8);
        }
    };

    // normalize (in-range rows only) + publish regs to LDS buffer `buf`
    auto write_regs = [&](int ch, int buf) {
        const bool applyN = (ch < CAc) ? nA : nB;
        #pragma unroll
        for (int k = 0; k < XPC; ++k) {
            const int r = tid + k * 256;
            if (r < SEG * 4) {
                const int pi = r >> 2, part = r & 3;
                const int gp = x0 + pi;
                short8 v = xr[k];
                if (applyN && gp >= 0 && gp < L_in) {
                    const int cb = ch * 32 + part * 8;
                    #pragma unroll
                    for (int e = 0; e < 8; ++e) {
                        float f = bf2f((unsigned short)v[e]);
                        f = lrelu(fmaf(f, csc[cb + e], csh[cb + e]));
                        v[e] = (short)f2bf(f);
                    }
                }
                *(short8*)(x_tile[buf] + pi * XPAD + part * 8) = v;
            }
        }
        #pragma unroll
        for (int k = 0; k < 3; ++k) {
            const int r = tid + k * 256;
            const int part = r & 3;
            const int co   = (r >> 2) & 63;
            const int t    = r >> 8;
            *(short8*)(w_tile[buf] + (t * 64 + co) * XPAD + part * 8) = wr3[k];
        }
    };

    load_regs(0);          // loads in flight across the barrier
    __syncthreads();       // csc/csh + stats init visible
    write_regs(0, 0);
    __syncthreads();       // buf0 ready

    for (int ch = 0; ch < nch; ++ch) {
        const int cur = ch & 1;
        if (ch + 1 < nch) load_regs(ch + 1);   // issue only; no wait

        #pragma unroll
        for (int t = 0; t < 3; ++t) {
            short8 bfr[4];
            #pragma unroll
            for (int s = 0; s < 4; ++s)
                bfr[s] = *(const short8*)(w_tile[cur] + (t * 64 + s * 16 + col) * XPAD + quad * 8);
            #pragma unroll
            for (int ps = 0; ps < 2; ++ps) {
                const int xi = (wv * 32 + ps * 16 + col) * STRIDE + t;
                short8 afr = *(const short8*)(x_tile[cur] + xi * XPAD + quad * 8);
                #pragma unroll
                for (int s = 0; s < 4; ++s)
                    acc[ps][s] = __builtin_amdgcn_mfma_f32_16x16x32_bf16(afr, bfr[s], acc[ps][s], 0, 0, 0);
            }
        }
        if (ch + 1 < nch) write_regs(ch + 1, cur ^ 1);  // vmcnt wait lands here
        __syncthreads();
    }

    float bv[4];
    #pragma unroll
    for (int s = 0; s < 4; ++s) bv[s] = bias[cob + s * 16 + col];
    #pragma unroll
    for (int ps = 0; ps < 2; ++ps)
        #pragma unroll
        for (int s = 0; s < 4; ++s)
            #pragma unroll
            for (int r = 0; r < 4; ++r)
                acc[ps][s][r] += bv[s];

    #pragma unroll
    for (int ps = 0; ps < 2; ++ps) {
        const int pos0 = oblk + wv * 32 + ps * 16 + quad * 4;
        #pragma unroll
        for (int s = 0; s < 4; ++s) {
            unsigned short* op = out + ((size_t)b * L_out + pos0) * Cout + cob + s * 16 + col;
            #pragma unroll
            for (int r = 0; r < 4; ++r)
                op[(size_t)r * Cout] = f2bf(acc[ps][s][r]);
        }
    }

    #pragma unroll
    for (int s = 0; s < 4; ++s) {
        float v = 0.f, q = 0.f;
        #pragma unroll
        for (int ps = 0; ps < 2; ++ps)
            #pragma unroll
            for (int r = 0; r < 4; ++r) {
                float a = acc[ps][s][r];
                v += a; q = fmaf(a, a, q);
            }
        v += __shfl_xor(v, 16); v += __shfl_xor(v, 32);
        q += __shfl_xor(q, 16); q += __shfl_xor(q, 32);
        if (quad == 0) {
            atomicAdd(&ssum[s * 16 + col], v);
            atomicAdd(&ssq[s * 16 + col],  q);
        }
    }
    __syncthreads();
    if (tid < 64) {
        atomicAdd(&st[cob + tid],       ssum[tid]);
        atomicAdd(&st[256 + cob + tid], ssq[tid]);
    }
}

// ---------------------------------------------------------------------------
// Banded correlation fusion on RAW f2 (BN+lrelu at staging). Block = 32
// positions x 1 batch (512 blocks); thread = (pos, 32-ch eighth).
// ---------------------------------------------------------------------------
__global__ __launch_bounds__(256) void fusion_kernel(
    const unsigned short* __restrict__ f2,
    const float* __restrict__ st, const float* __restrict__ g,
    const float* __restrict__ be, float invN,
    unsigned short* __restrict__ feat)
{
    constexpr int ROWS = 44;
    constexpr int CPAD = 272;
    __shared__ __align__(16) unsigned short tile[ROWS * CPAD];
    __shared__ float csc[256], csh[256];
    const int tid = threadIdx.x;
    const int p0  = blockIdx.x * 32;
    const int b   = blockIdx.y;
    const unsigned short* base = f2 + (size_t)b * 2048 * 256;

    {
        float sc, sh;
        bn_coeff(st, g, be, invN, tid, sc, sh);
        csc[tid] = sc; csh[tid] = sh;
    }
    __syncthreads();
    float scr[8], shr[8];
    {
        const int cb = (tid & 31) * 8;
        #pragma unroll
        for (int e = 0; e < 8; ++e) { scr[e] = csc[cb + e]; shr[e] = csh[cb + e]; }
    }
    for (int r = tid; r < ROWS * 32; r += 256) {
        int row = r >> 5, piece = r & 31;
        int grow = min(max(p0 - 6 + row, 0), 2047);
        short8 v = *(const short8*)(base + (size_t)grow * 256 + piece * 8);
        #pragma unroll
        for (int e = 0; e < 8; ++e) {
            float f = bf2f((unsigned short)v[e]);
            f = lrelu(fmaf(f, scr[e], shr[e]));
            v[e] = (short)f2bf(f);
        }
        *(short8*)(tile + row * CPAD + piece * 8) = v;
    }
    __syncthreads();

    const int il = tid >> 3;
    const int q  = tid & 7;
    const int i  = p0 + il;

    float acc[11];
    #pragma unroll
    for (int d = 0; d < 11; ++d) acc[d] = 0.f;

    int ra[3];
    #pragma unroll
    for (int j = 0; j < 3; ++j)
        ra[j] = (min(max(i + j - 1, 0), 2047) - p0 + 6) * CPAD;
    int rb[11][3];
    #pragma unroll
    for (int d = 0; d < 11; ++d) {
        int i2 = min(max(i + d - 5, 0), 2047);
        #pragma unroll
        for (int j = 0; j < 3; ++j)
            rb[d][j] = (min(max(i2 + j - 1, 0), 2047) - p0 + 6) * CPAD;
    }

    for (int ck = 0; ck < 4; ++ck) {
        const int coff = q * 32 + ck * 8;
        float fa[3][8];
        #pragma unroll
        for (int j = 0; j < 3; ++j) {
            short8 v = *(const short8*)(tile + ra[j] + coff);
            #pragma unroll
            for (int e = 0; e < 8; ++e) fa[j][e] = bf2f((unsigned short)v[e]);
        }
        #pragma unroll
        for (int d = 0; d < 11; ++d) {
            #pragma unroll
            for (int j = 0; j < 3; ++j) {
                short8 v = *(const short8*)(tile + rb[d][j] + coff);
                #pragma unroll
                for (int e = 0; e < 8; ++e)
                    acc[d] = fmaf(fa[j][e], bf2f((unsigned short)v[e]), acc[d]);
            }
        }
    }

    #pragma unroll
    for (int d = 0; d < 11; ++d) {
        acc[d] += __shfl_xor(acc[d], 1);
        acc[d] += __shfl_xor(acc[d], 2);
        acc[d] += __shfl_xor(acc[d], 4);
    }
    if (q == 0) {
        unsigned short* op = feat + ((size_t)(b * 2048 + i)) * 32;
        #pragma unroll
        for (int d = 0; d < 11; ++d) op[d] = f2bf(acc[d]);
        #pragma unroll
        for (int d = 11; d < 32; ++d) op[d] = 0;
    }
}

// ---------------------------------------------------------------------------
// Flow head (K=1, Cout=2) on raw d0 (BN+lrelu inline) + stats.
// ---------------------------------------------------------------------------
__global__ __launch_bounds__(256) void flow_kernel(
    const float* __restrict__ scan1, const unsigned short* __restrict__ d0,
    const float* __restrict__ st4, const float* __restrict__ g4,
    const float* __restrict__ be4, float invN4,
    const float* __restrict__ fw, const float* __restrict__ fb,
    float* __restrict__ outr, float* __restrict__ st)
{
    __shared__ float s4[4][4];
    __shared__ float csc[128], csh[128];
    const int tid = threadIdx.x;
    const int b = blockIdx.z;
    const int i = blockIdx.x * 256 + tid;
    if (tid < 128) {
        float sc, sh;
        bn_coeff(st4, g4, be4, invN4, tid, sc, sh);
        csc[tid] = sc; csh[tid] = sh;
    }
    __syncthreads();
    float sv = scan1[(size_t)b * 16384 + i];
    const unsigned short* row = d0 + ((size_t)(b * 8192 + (i >> 1))) * 128;
    float a0 = fmaf(fw[0],   sv, fb[0]);
    float a1 = fmaf(fw[129], sv, fb[1]);
    for (int c8 = 0; c8 < 16; ++c8) {
        short8 v = *(const short8*)(row + c8 * 8);
        #pragma unroll
        for (int j = 0; j < 8; ++j) {
            int cc = c8 * 8 + j;
            float f = bf2f((unsigned short)v[j]);
            f = lrelu(fmaf(f, csc[cc], csh[cc]));
            a0 = fmaf(fw[1 + cc],   f, a0);
            a1 = fmaf(fw[130 + cc], f, a1);
        }
    }
    float2 o; o.x = a0; o.y = a1;
    *(float2*)(outr + ((size_t)(b * 16384 + i)) * 2) = o;
    float s0 = a0, q0 = a0 * a0, s1 = a1, q1 = a1 * a1;
    #pragma unroll
    for (int off = 1; off < 64; off <<= 1) {
        s0 += __shfl_xor(s0, off); q0 += __shfl_xor(q0, off);
        s1 += __shfl_xor(s1, off); q1 += __shfl_xor(q1, off);
    }
    if ((tid & 63) == 0) {
        int w = tid >> 6;
        s4[w][0] = s0; s4[w][1] = q0; s4[w][2] = s1; s4[w][3] = q1;
    }
    __syncthreads();
    if (tid == 0) {
        float t0 = 0, t1 = 0, t2 = 0, t3 = 0;
        for (int w = 0; w < 4; ++w) {
            t0 += s4[w][0]; t1 += s4[w][1]; t2 += s4[w][2]; t3 += s4[w][3];
        }
        atomicAdd(&st[0],   t0); atomicAdd(&st[256],     t1);
        atomicAdd(&st[1],   t2); atomicAdd(&st[256 + 1], t3);
    }
}

// Final: BN + lrelu on flow raw -> d_out (B,N,2) fp32.
__global__ __launch_bounds__(256) void final_kernel(
    const float* __restrict__ raw, const float* __restrict__ st,
    const float* __restrict__ g, const float* __restrict__ be,
    float invN, float* __restrict__ out)
{
    int idx = blockIdx.x * 256 + threadIdx.x;
    float sc0, sh0, sc1, sh1;
    bn_coeff(st, g, be, invN, 0, sc0, sh0);
    bn_coeff(st, g, be, invN, 1, sc1, sh1);
    float2 v = *(const float2*)(raw + (size_t)idx * 2);
    float2 o;
    o.x = lrelu(fmaf(v.x, sc0, sh0));
    o.y = lrelu(fmaf(v.y, sc1, sh1));
    *(float2*)(out + (size_t)idx * 2) = o;
}

// ---------------------------------------------------------------------------

extern "C" void kernel_launch(void* const* d_in, const int* in_sizes, int n_in,
                              void* d_out, int out_size, void* d_ws, size_t ws_size,
                              hipStream_t stream)
{
    const int B = 8;
    const float* scan1 = (const float*)d_in[0];
    const float* enc0_w = (const float*)d_in[1];
    const float* enc0_b = (const float*)d_in[2];
    const float* enc0_g = (const float*)d_in[3];
    const float* enc0_be= (const float*)d_in[4];
    const float* enc1_w = (const float*)d_in[5];
    const float* enc1_b = (const float*)d_in[6];
    const float* enc1_g = (const float*)d_in[7];
    const float* enc1_be= (const float*)d_in[8];
    const float* enc2_w = (const float*)d_in[9];
    const float* enc2_b = (const float*)d_in[10];
    const float* enc2_g = (const float*)d_in[11];
    const float* enc2_be= (const float*)d_in[12];
    const float* dec1_w = (const float*)d_in[13];
    const float* dec1_b = (const float*)d_in[14];
    const float* dec1_g = (const float*)d_in[15];
    const float* dec1_be= (const float*)d_in[16];
    const float* dec0_w = (const float*)d_in[17];
    const float* dec0_b = (const float*)d_in[18];
    const float* dec0_g = (const float*)d_in[19];
    const float* dec0_be= (const float*)d_in[20];
    const float* flow_w = (const float*)d_in[21];
    const float* flow_b = (const float*)d_in[22];
    const float* flow_g = (const float*)d_in[23];
    const float* flow_be= (const float*)d_in[24];

    char* ws = (char*)d_ws;
    unsigned short* f0    = (unsigned short*)(ws);             // [8][8192][64] raw
    unsigned short* f1    = (unsigned short*)(ws + 8388608);   // [8][4096][128] raw
    unsigned short* f2    = (unsigned short*)(ws + 16777216);  // [8][2048][256] raw
    unsigned short* featn = (unsigned short*)(ws + 25165824);  // [8][2048][32]
    unsigned short* d1    = (unsigned short*)(ws + 26214400);  // [8][4096][128] raw
    unsigned short* d0    = (unsigned short*)(ws + 34603008);  // [8][8192][128] raw
    float*  flow_r = (float*)(ws + 51380224);                  // [8][16384][2]
    unsigned short* wr1 = (unsigned short*)(ws + 52428800);    // [3][128][64]
    unsigned short* wr2 = (unsigned short*)(ws + 52477952);    // [3][256][128]
    unsigned short* wr3 = (unsigned short*)(ws + 52674560);    // [3][128][160]
    unsigned short* wr4 = (unsigned short*)(ws + 52797440);    // [3][128][192]
    float* st = (float*)(ws + 52944896);                       // 6 x 512 floats
    float* st0 = st, *st1 = st + 512, *st2 = st + 1024;
    float* st3 = st + 1536, *st4 = st + 2048, *st5 = st + 2560;

    const float iN0 = 1.0f / (B * 8192.0f);
    const float iN1 = 1.0f / (B * 4096.0f);
    const float iN2 = 1.0f / (B * 2048.0f);
    const float iN3 = 1.0f / (B * 4096.0f);
    const float iN4 = 1.0f / (B * 8192.0f);
    const float iN5 = 1.0f / (B * 16384.0f);

    hipMemsetAsync(st, 0, 6 * 512 * sizeof(float), stream);

    // fused enc0 (blocks 0..511) + weight reorder (blocks 512..1519)
    enc0_prepw_kernel<<<1520, 256, 0, stream>>>(
        scan1, enc0_w, enc0_b, f0, st0,
        enc1_w, wr1, enc2_w, wr2, dec1_w, wr3, dec0_w, wr4);

    // enc1 (MFMA, stride 2): norm(f0; st0) -> f1 raw + st1
    conv_mfma_kernel<2><<<dim3(32, 2, B), 256, 0, stream>>>(
        f0, 2, st0, enc0_g, enc0_be, iN0,
        nullptr, 0, nullptr, nullptr, nullptr, 0.f,
        wr1, enc1_b, f1, 8192, 4096, 128, st1);

    // enc2 (MFMA, stride 2): norm(f1; st1) -> f2 raw + st2
    conv_mfma_kernel<2><<<dim3(16, 4, B), 256, 0, stream>>>(
        f1, 4, st1, enc1_g, enc1_be, iN1,
        nullptr, 0, nullptr, nullptr, nullptr, 0.f,
        wr2, enc2_b, f2, 4096, 2048, 256, st2);

    // fusion: banded correlation on norm(f2; st2)
    fusion_kernel<<<dim3(64, B), 256, 0, stream>>>(f2, st2, enc2_g, enc2_be, iN2, featn);

    // dec1 (MFMA, stride 1): concat(norm(f1; st1), up2(featn raw)) -> d1 raw + st3
    conv_mfma_kernel<1><<<dim3(32, 2, B), 256, 0, stream>>>(
        f1, 4, st1, enc1_g, enc1_be, iN1,
        featn, 1, nullptr, nullptr, nullptr, 0.f,
        wr3, dec1_b, d1, 4096, 4096, 128, st3);

    // dec0 (MFMA, stride 1): concat(norm(f0; st0), up2(norm(d1; st3))) -> d0 raw + st4
    conv_mfma_kernel<1><<<dim3(64, 2, B), 256, 0, stream>>>(
        f0, 2, st0, enc0_g, enc0_be, iN0,
        d1, 4, st3, dec1_g, dec1_be, iN3,
        wr4, dec0_b, d0, 8192, 8192, 128, st4);

    // flow head (VALU): concat(scan1, up2(norm(d0; st4))) -> flow_r + st5
    flow_kernel<<<dim3(64, 1, B), 256, 0, stream>>>(
        scan1, d0, st4, dec0_g, dec0_be, iN4, flow_w, flow_b, flow_r, st5);

    // final BN + lrelu -> d_out
    final_kernel<<<512, 256, 0, stream>>>(flow_r, st5, flow_g, flow_be, iN5, (float*)d_out);
}

// Round 18
// 243.674 us; speedup vs baseline: 1.1128x; 1.0109x over previous
//
#include <hip/hip_runtime.h>
#include <cstddef>

#define SLOPE 0.01f
#define BN_EPS 1e-5f

typedef __attribute__((ext_vector_type(8))) short short8;
typedef __attribute__((ext_vector_type(4))) float floatx4;

__device__ __forceinline__ float lrelu(float t) { return fmaxf(t, SLOPE * t); }

__device__ __forceinline__ unsigned short f2bf(float f) {
    union { float f; unsigned int u; } x; x.f = f;
    unsigned int r = (x.u + 0x7fff + ((x.u >> 16) & 1)) >> 16;   // RNE
    return (unsigned short)r;
}
__device__ __forceinline__ float bf2f(unsigned short h) {
    union { unsigned int u; float f; } x; x.u = ((unsigned int)h) << 16;
    return x.f;
}

// BN affine for channel c from raw sums. st: [sum(256) | sumsq(256)].
__device__ __forceinline__ void bn_coeff(const float* __restrict__ st,
                                         const float* __restrict__ g,
                                         const float* __restrict__ be,
                                         float invN, int c, float& sc, float& sh) {
    float m   = st[c] * invN;
    float var = fmaf(st[256 + c], invN, -m * m);
    float r   = rsqrtf(var + BN_EPS);
    sc = g[c] * r;
    sh = fmaf(-sc, m, be[c]);
}

// ---------------------------------------------------------------------------
// Fused: enc0 conv (blocks 0..511) + weight reorder for all 4 MFMA layers
// (blocks 512..1519). Independent work; prepw outputs first consumed by the
// NEXT dispatch (enc1). Saves one launch.
// ---------------------------------------------------------------------------
__device__ __forceinline__ void reorder1(const float* __restrict__ w,
                                         unsigned short* __restrict__ wr,
                                         int Cout, int Cinpad, int Cin, int id) {
    int ci = id % Cinpad;
    int rest = id / Cinpad;
    int co = rest % Cout;
    int t  = rest / Cout;
    float v = (ci < Cin) ? w[((size_t)co * Cin + ci) * 3 + t] : 0.0f;
    wr[id] = f2bf(v);
}

__global__ __launch_bounds__(256) void enc0_prepw_kernel(
    const float* __restrict__ x, const float* __restrict__ w,
    const float* __restrict__ bias, unsigned short* __restrict__ f0,
    float* __restrict__ st,
    const float* __restrict__ w1, unsigned short* __restrict__ o1,
    const float* __restrict__ w2, unsigned short* __restrict__ o2,
    const float* __restrict__ w3, unsigned short* __restrict__ o3,
    const float* __restrict__ w4, unsigned short* __restrict__ o4)
{
    const int tid = threadIdx.x;
    const int bx  = blockIdx.x;

    if (bx >= 512) {                    // ---- weight reorder part ----
        int id = (bx - 512) * 256 + tid;
        const int n1 = 3 * 128 * 64;
        const int n2 = 3 * 256 * 128;
        const int n3 = 3 * 128 * 160;
        const int n4 = 3 * 128 * 192;
        if (id < n1) { reorder1(w1, o1, 128, 64, 64, id); return; }
        id -= n1;
        if (id < n2) { reorder1(w2, o2, 256, 128, 128, id); return; }
        id -= n2;
        if (id < n3) { reorder1(w3, o3, 128, 160, 139, id); return; }
        id -= n3;
        if (id < n4) { reorder1(w4, o4, 128, 192, 192, id); return; }
        return;
    }

    // ---- enc0 part: (B,1,16384) -> raw bf16 f0 [b][8192][64] + stats ----
    __shared__ float ssum[64], ssq[64];
    const int co = tid & 63;
    const int b  = bx >> 6;
    const int xb = bx & 63;
    if (tid < 64) { ssum[tid] = 0.f; ssq[tid] = 0.f; }
    __syncthreads();
    const float w0 = w[co * 3], w1c = w[co * 3 + 1], w2c = w[co * 3 + 2];
    const float bs = bias[co];
    const float* xbp = x + (size_t)b * 16384;
    float lsum = 0.f, lsq = 0.f;
    const int obase = xb * 128 + (tid >> 6) * 32;
    for (int k = 0; k < 32; ++k) {
        int o = obase + k;
        int xi = 2 * o - 1;
        float x0v = (xi >= 0) ? xbp[xi] : 0.f;
        float a = bs;
        a = fmaf(w0, x0v, a);
        a = fmaf(w1c, xbp[xi + 1], a);
        a = fmaf(w2c, xbp[xi + 2], a);
        f0[((size_t)(b * 8192 + o)) * 64 + co] = f2bf(a);
        lsum += a; lsq = fmaf(a, a, lsq);
    }
    atomicAdd(&ssum[co], lsum);
    atomicAdd(&ssq[co], lsq);
    __syncthreads();
    if (tid < 64) {
        atomicAdd(&st[tid],       ssum[tid]);
        atomicAdd(&st[256 + tid], ssq[tid]);
    }
}

// ---------------------------------------------------------------------------
// MFMA implicit-GEMM conv, channel-last bf16, depth-1 register pipeline
// (R15 — measured best): per chunk: (1) issue ch+1 global loads into
// FIXED-TRIP unrolled register arrays; (2) MFMA(ch) from LDS; (3) norm +
// ds_write regs into other buffer (vmcnt wait after MFMA); (4) one barrier.
// x/w tiles double-buffered, 36-short padded rows. Padding rows stay zero.
// M-tile = 128 pos x 64 co. Grid: (L_out/128, Cout/64, B).
// ---------------------------------------------------------------------------
template<int STRIDE>
__global__ __launch_bounds__(256) void conv_mfma_kernel(
    const unsigned short* __restrict__ xA, int CAc,
    const float* __restrict__ stA, const float* __restrict__ gA,
    const float* __restrict__ beA, float invNA,
    const unsigned short* __restrict__ xB, int CBc,
    const float* __restrict__ stB, const float* __restrict__ gB,
    const float* __restrict__ beB, float invNB,
    const unsigned short* __restrict__ Wr, const float* __restrict__ bias,
    unsigned short* __restrict__ out, int L_in, int L_out, int Cout,
    float* __restrict__ st)
{
    constexpr int SEG  = 127 * STRIDE + 3;
    constexpr int XPC  = (SEG * 4 + 255) / 256;
    constexpr int XPAD = 36;
    __shared__ __align__(16) unsigned short x_tile[2][SEG * XPAD];
    __shared__ __align__(16) unsigned short w_tile[2][3 * 64 * XPAD];
    __shared__ float ssum[64], ssq[64];
    __shared__ float csc[192], csh[192];

    const int tid  = threadIdx.x;
    const int wv   = tid >> 6;
    const int lane = tid & 63;
    const int col  = lane & 15;
    const int quad = lane >> 4;
    const int oblk = blockIdx.x * 128;
    const int cob  = blockIdx.y * 64;
    const int b    = blockIdx.z;
    const int nch    = CAc + CBc;
    const int CApad  = CAc * 32;
    const int CBpad  = CBc * 32;
    const int Cinpad = nch * 32;
    const int LB     = L_in >> 1;
    const bool nA = (stA != nullptr);
    const bool nB = (stB != nullptr);

    if (tid < 64) { ssum[tid] = 0.f; ssq[tid] = 0.f; }
    for (int c = tid; c < Cinpad; c += 256) {
        float sc = 1.f, sh = 0.f;
        if (c < CApad) { if (nA) bn_coeff(stA, gA, beA, invNA, c, sc, sh); }
        else           { if (nB) bn_coeff(stB, gB, beB, invNB, c - CApad, sc, sh); }
        csc[c] = sc; csh[c] = sh;
    }

    floatx4 acc[2][4];
    #pragma unroll
    for (int ps = 0; ps < 2; ++ps)
        #pragma unroll
        for (int s = 0; s < 4; ++s)
            acc[ps][s] = (floatx4){0.f, 0.f, 0.f, 0.f};

    const int x0 = oblk * STRIDE - 1;

    short8 xr[XPC];
    short8 wr3[3];

    auto load_regs = [&](int ch) {
        #pragma unroll
        for (int k = 0; k < XPC; ++k) {
            const int r = tid + k * 256;
            short8 v = {0, 0, 0, 0, 0, 0, 0, 0};
            if (r < SEG * 4) {
                const int pi = r >> 2, part = r & 3;
                const int gp = x0 + pi;
                if (gp >= 0 && gp < L_in) {
                    if (ch < CAc)
                        v = *(const short8*)(xA + ((size_t)b * L_in + gp) * CApad + ch * 32 + part * 8);
                    else
                        v = *(const short8*)(xB + ((size_t)b * LB + (gp >> 1)) * CBpad + (ch - CAc) * 32 + part * 8);
                }
            }
            xr[k] = v;
        }
        #pragma unroll
        for (int k = 0; k < 3; ++k) {     // 768 = 3*256 exactly
            const int r = tid + k * 256;
            const int part = r & 3;
            const int co   = (r >> 2) & 63;
            const int t    = r >> 8;
            wr3[k] = *(const short8*)(Wr + ((size_t)(t * Cout + cob + co)) * Cinpad + ch * 32 + part * 8);
        }
    };

    auto write_regs = [&](int ch, int buf) {
        const bool applyN = (ch < CAc) ? nA : nB;
        #pragma unroll
        for (int k = 0; k < XPC; ++k) {
            const int r = tid + k * 256;
            if (r < SEG * 4) {
                const int pi = r >> 2, part = r & 3;
                const int gp = x0 + pi;
                short8 v = xr[k];
                if (applyN && gp >= 0 && gp < L_in) {
                    const int cb = ch * 32 + part * 8;
                    #pragma unroll
                    for (int e = 0; e < 8; ++e) {
                        float f = bf2f((unsigned short)v[e]);
                        f = lrelu(fmaf(f, csc[cb + e], csh[cb + e]));
                        v[e] = (short)f2bf(f);
                    }
                }
                *(short8*)(x_tile[buf] + pi * XPAD + part * 8) = v;
            }
        }
        #pragma unroll
        for (int k = 0; k < 3; ++k) {
            const int r = tid + k * 256;
            const int part = r & 3;
            const int co   = (r >> 2) & 63;
            const int t    = r >> 8;
            *(short8*)(w_tile[buf] + (t * 64 + co) * XPAD + part * 8) = wr3[k];
        }
    };

    load_regs(0);          // loads in flight across the barrier
    __syncthreads();       // csc/csh + stats init visible
    write_regs(0, 0);
    __syncthreads();       // buf0 ready

    for (int ch = 0; ch < nch; ++ch) {
        const int cur = ch & 1;
        if (ch + 1 < nch) load_regs(ch + 1);   // issue only; no wait

        #pragma unroll
        for (int t = 0; t < 3; ++t) {
            short8 bfr[4];
            #pragma unroll
            for (int s = 0; s < 4; ++s)
                bfr[s] = *(const short8*)(w_tile[cur] + (t * 64 + s * 16 + col) * XPAD + quad * 8);
            #pragma unroll
            for (int ps = 0; ps < 2; ++ps) {
                const int xi = (wv * 32 + ps * 16 + col) * STRIDE + t;
                short8 afr = *(const short8*)(x_tile[cur] + xi * XPAD + quad * 8);
                #pragma unroll
                for (int s = 0; s < 4; ++s)
                    acc[ps][s] = __builtin_amdgcn_mfma_f32_16x16x32_bf16(afr, bfr[s], acc[ps][s], 0, 0, 0);
            }
        }
        if (ch + 1 < nch) write_regs(ch + 1, cur ^ 1);  // vmcnt wait lands here
        __syncthreads();
    }

    float bv[4];
    #pragma unroll
    for (int s = 0; s < 4; ++s) bv[s] = bias[cob + s * 16 + col];
    #pragma unroll
    for (int ps = 0; ps < 2; ++ps)
        #pragma unroll
        for (int s = 0; s < 4; ++s)
            #pragma unroll
            for (int r = 0; r < 4; ++r)
                acc[ps][s][r] += bv[s];

    #pragma unroll
    for (int ps = 0; ps < 2; ++ps) {
        const int pos0 = oblk + wv * 32 + ps * 16 + quad * 4;
        #pragma unroll
        for (int s = 0; s < 4; ++s) {
            unsigned short* op = out + ((size_t)b * L_out + pos0) * Cout + cob + s * 16 + col;
            #pragma unroll
            for (int r = 0; r < 4; ++r)
                op[(size_t)r * Cout] = f2bf(acc[ps][s][r]);
        }
    }

    #pragma unroll
    for (int s = 0; s < 4; ++s) {
        float v = 0.f, q = 0.f;
        #pragma unroll
        for (int ps = 0; ps < 2; ++ps)
            #pragma unroll
            for (int r = 0; r < 4; ++r) {
                float a = acc[ps][s][r];
                v += a; q = fmaf(a, a, q);
            }
        v += __shfl_xor(v, 16); v += __shfl_xor(v, 32);
        q += __shfl_xor(q, 16); q += __shfl_xor(q, 32);
        if (quad == 0) {
            atomicAdd(&ssum[s * 16 + col], v);
            atomicAdd(&ssq[s * 16 + col],  q);
        }
    }
    __syncthreads();
    if (tid < 64) {
        atomicAdd(&st[cob + tid],       ssum[tid]);
        atomicAdd(&st[256 + cob + tid], ssq[tid]);
    }
}

// ---------------------------------------------------------------------------
// Banded correlation fusion on RAW f2 (BN+lrelu at staging). Block = 32
// positions x 1 batch (512 blocks); thread = (pos, 32-ch eighth).
// CPAD = 264 shorts = 132 dwords (mod 32 = 4): wave rows start at banks
// {0,4,..,28} uniformly — halves the bank conflicts vs 272 (mod 32 = 8).
// ---------------------------------------------------------------------------
__global__ __launch_bounds__(256) void fusion_kernel(
    const unsigned short* __restrict__ f2,
    const float* __restrict__ st, const float* __restrict__ g,
    const float* __restrict__ be, float invN,
    unsigned short* __restrict__ feat)
{
    constexpr int ROWS = 44;
    constexpr int CPAD = 264;
    __shared__ __align__(16) unsigned short tile[ROWS * CPAD];
    __shared__ float csc[256], csh[256];
    const int tid = threadIdx.x;
    const int p0  = blockIdx.x * 32;
    const int b   = blockIdx.y;
    const unsigned short* base = f2 + (size_t)b * 2048 * 256;

    {
        float sc, sh;
        bn_coeff(st, g, be, invN, tid, sc, sh);
        csc[tid] = sc; csh[tid] = sh;
    }
    __syncthreads();
    float scr[8], shr[8];
    {
        const int cb = (tid & 31) * 8;
        #pragma unroll
        for (int e = 0; e < 8; ++e) { scr[e] = csc[cb + e]; shr[e] = csh[cb + e]; }
    }
    for (int r = tid; r < ROWS * 32; r += 256) {
        int row = r >> 5, piece = r & 31;
        int grow = min(max(p0 - 6 + row, 0), 2047);
        short8 v = *(const short8*)(base + (size_t)grow * 256 + piece * 8);
        #pragma unroll
        for (int e = 0; e < 8; ++e) {
            float f = bf2f((unsigned short)v[e]);
            f = lrelu(fmaf(f, scr[e], shr[e]));
            v[e] = (short)f2bf(f);
        }
        *(short8*)(tile + row * CPAD + piece * 8) = v;
    }
    __syncthreads();

    const int il = tid >> 3;
    const int q  = tid & 7;
    const int i  = p0 + il;

    float acc[11];
    #pragma unroll
    for (int d = 0; d < 11; ++d) acc[d] = 0.f;

    int ra[3];
    #pragma unroll
    for (int j = 0; j < 3; ++j)
        ra[j] = (min(max(i + j - 1, 0), 2047) - p0 + 6) * CPAD;
    int rb[11][3];
    #pragma unroll
    for (int d = 0; d < 11; ++d) {
        int i2 = min(max(i + d - 5, 0), 2047);
        #pragma unroll
        for (int j = 0; j < 3; ++j)
            rb[d][j] = (min(max(i2 + j - 1, 0), 2047) - p0 + 6) * CPAD;
    }

    for (int ck = 0; ck < 4; ++ck) {
        const int coff = q * 32 + ck * 8;
        float fa[3][8];
        #pragma unroll
        for (int j = 0; j < 3; ++j) {
            short8 v = *(const short8*)(tile + ra[j] + coff);
            #pragma unroll
            for (int e = 0; e < 8; ++e) fa[j][e] = bf2f((unsigned short)v[e]);
        }
        #pragma unroll
        for (int d = 0; d < 11; ++d) {
            #pragma unroll
            for (int j = 0; j < 3; ++j) {
                short8 v = *(const short8*)(tile + rb[d][j] + coff);
                #pragma unroll
                for (int e = 0; e < 8; ++e)
                    acc[d] = fmaf(fa[j][e], bf2f((unsigned short)v[e]), acc[d]);
            }
        }
    }

    #pragma unroll
    for (int d = 0; d < 11; ++d) {
        acc[d] += __shfl_xor(acc[d], 1);
        acc[d] += __shfl_xor(acc[d], 2);
        acc[d] += __shfl_xor(acc[d], 4);
    }
    if (q == 0) {
        unsigned short* op = feat + ((size_t)(b * 2048 + i)) * 32;
        #pragma unroll
        for (int d = 0; d < 11; ++d) op[d] = f2bf(acc[d]);
        #pragma unroll
        for (int d = 11; d < 32; ++d) op[d] = 0;
    }
}

// ---------------------------------------------------------------------------
// Flow head (K=1, Cout=2) on raw d0 (BN+lrelu inline) + stats.
// ---------------------------------------------------------------------------
__global__ __launch_bounds__(256) void flow_kernel(
    const float* __restrict__ scan1, const unsigned short* __restrict__ d0,
    const float* __restrict__ st4, const float* __restrict__ g4,
    const float* __restrict__ be4, float invN4,
    const float* __restrict__ fw, const float* __restrict__ fb,
    float* __restrict__ outr, float* __restrict__ st)
{
    __shared__ float s4[4][4];
    __shared__ float csc[128], csh[128];
    const int tid = threadIdx.x;
    const int b = blockIdx.z;
    const int i = blockIdx.x * 256 + tid;
    if (tid < 128) {
        float sc, sh;
        bn_coeff(st4, g4, be4, invN4, tid, sc, sh);
        csc[tid] = sc; csh[tid] = sh;
    }
    __syncthreads();
    float sv = scan1[(size_t)b * 16384 + i];
    const unsigned short* row = d0 + ((size_t)(b * 8192 + (i >> 1))) * 128;
    float a0 = fmaf(fw[0],   sv, fb[0]);
    float a1 = fmaf(fw[129], sv, fb[1]);
    for (int c8 = 0; c8 < 16; ++c8) {
        short8 v = *(const short8*)(row + c8 * 8);
        #pragma unroll
        for (int j = 0; j < 8; ++j) {
            int cc = c8 * 8 + j;
            float f = bf2f((unsigned short)v[j]);
            f = lrelu(fmaf(f, csc[cc], csh[cc]));
            a0 = fmaf(fw[1 + cc],   f, a0);
            a1 = fmaf(fw[130 + cc], f, a1);
        }
    }
    float2 o; o.x = a0; o.y = a1;
    *(float2*)(outr + ((size_t)(b * 16384 + i)) * 2) = o;
    float s0 = a0, q0 = a0 * a0, s1 = a1, q1 = a1 * a1;
    #pragma unroll
    for (int off = 1; off < 64; off <<= 1) {
        s0 += __shfl_xor(s0, off); q0 += __shfl_xor(q0, off);
        s1 += __shfl_xor(s1, off); q1 += __shfl_xor(q1, off);
    }
    if ((tid & 63) == 0) {
        int w = tid >> 6;
        s4[w][0] = s0; s4[w][1] = q0; s4[w][2] = s1; s4[w][3] = q1;
    }
    __syncthreads();
    if (tid == 0) {
        float t0 = 0, t1 = 0, t2 = 0, t3 = 0;
        for (int w = 0; w < 4; ++w) {
            t0 += s4[w][0]; t1 += s4[w][1]; t2 += s4[w][2]; t3 += s4[w][3];
        }
        atomicAdd(&st[0],   t0); atomicAdd(&st[256],     t1);
        atomicAdd(&st[1],   t2); atomicAdd(&st[256 + 1], t3);
    }
}

// Final: BN + lrelu on flow raw -> d_out (B,N,2) fp32.
__global__ __launch_bounds__(256) void final_kernel(
    const float* __restrict__ raw, const float* __restrict__ st,
    const float* __restrict__ g, const float* __restrict__ be,
    float invN, float* __restrict__ out)
{
    int idx = blockIdx.x * 256 + threadIdx.x;
    float sc0, sh0, sc1, sh1;
    bn_coeff(st, g, be, invN, 0, sc0, sh0);
    bn_coeff(st, g, be, invN, 1, sc1, sh1);
    float2 v = *(const float2*)(raw + (size_t)idx * 2);
    float2 o;
    o.x = lrelu(fmaf(v.x, sc0, sh0));
    o.y = lrelu(fmaf(v.y, sc1, sh1));
    *(float2*)(out + (size_t)idx * 2) = o;
}

// ---------------------------------------------------------------------------

extern "C" void kernel_launch(void* const* d_in, const int* in_sizes, int n_in,
                              void* d_out, int out_size, void* d_ws, size_t ws_size,
                              hipStream_t stream)
{
    const int B = 8;
    const float* scan1 = (const float*)d_in[0];
    const float* enc0_w = (const float*)d_in[1];
    const float* enc0_b = (const float*)d_in[2];
    const float* enc0_g = (const float*)d_in[3];
    const float* enc0_be= (const float*)d_in[4];
    const float* enc1_w = (const float*)d_in[5];
    const float* enc1_b = (const float*)d_in[6];
    const float* enc1_g = (const float*)d_in[7];
    const float* enc1_be= (const float*)d_in[8];
    const float* enc2_w = (const float*)d_in[9];
    const float* enc2_b = (const float*)d_in[10];
    const float* enc2_g = (const float*)d_in[11];
    const float* enc2_be= (const float*)d_in[12];
    const float* dec1_w = (const float*)d_in[13];
    const float* dec1_b = (const float*)d_in[14];
    const float* dec1_g = (const float*)d_in[15];
    const float* dec1_be= (const float*)d_in[16];
    const float* dec0_w = (const float*)d_in[17];
    const float* dec0_b = (const float*)d_in[18];
    const float* dec0_g = (const float*)d_in[19];
    const float* dec0_be= (const float*)d_in[20];
    const float* flow_w = (const float*)d_in[21];
    const float* flow_b = (const float*)d_in[22];
    const float* flow_g = (const float*)d_in[23];
    const float* flow_be= (const float*)d_in[24];

    char* ws = (char*)d_ws;
    unsigned short* f0    = (unsigned short*)(ws);             // [8][8192][64] raw
    unsigned short* f1    = (unsigned short*)(ws + 8388608);   // [8][4096][128] raw
    unsigned short* f2    = (unsigned short*)(ws + 16777216);  // [8][2048][256] raw
    unsigned short* featn = (unsigned short*)(ws + 25165824);  // [8][2048][32]
    unsigned short* d1    = (unsigned short*)(ws + 26214400);  // [8][4096][128] raw
    unsigned short* d0    = (unsigned short*)(ws + 34603008);  // [8][8192][128] raw
    float*  flow_r = (float*)(ws + 51380224);                  // [8][16384][2]
    unsigned short* wr1 = (unsigned short*)(ws + 52428800);    // [3][128][64]
    unsigned short* wr2 = (unsigned short*)(ws + 52477952);    // [3][256][128]
    unsigned short* wr3 = (unsigned short*)(ws + 52674560);    // [3][128][160]
    unsigned short* wr4 = (unsigned short*)(ws + 52797440);    // [3][128][192]
    float* st = (float*)(ws + 52944896);                       // 6 x 512 floats
    float* st0 = st, *st1 = st + 512, *st2 = st + 1024;
    float* st3 = st + 1536, *st4 = st + 2048, *st5 = st + 2560;

    const float iN0 = 1.0f / (B * 8192.0f);
    const float iN1 = 1.0f / (B * 4096.0f);
    const float iN2 = 1.0f / (B * 2048.0f);
    const float iN3 = 1.0f / (B * 4096.0f);
    const float iN4 = 1.0f / (B * 8192.0f);
    const float iN5 = 1.0f / (B * 16384.0f);

    hipMemsetAsync(st, 0, 6 * 512 * sizeof(float), stream);

    // fused enc0 (blocks 0..511) + weight reorder (blocks 512..1519)
    enc0_prepw_kernel<<<1520, 256, 0, stream>>>(
        scan1, enc0_w, enc0_b, f0, st0,
        enc1_w, wr1, enc2_w, wr2, dec1_w, wr3, dec0_w, wr4);

    // enc1 (MFMA, stride 2): norm(f0; st0) -> f1 raw + st1
    conv_mfma_kernel<2><<<dim3(32, 2, B), 256, 0, stream>>>(
        f0, 2, st0, enc0_g, enc0_be, iN0,
        nullptr, 0, nullptr, nullptr, nullptr, 0.f,
        wr1, enc1_b, f1, 8192, 4096, 128, st1);

    // enc2 (MFMA, stride 2): norm(f1; st1) -> f2 raw + st2
    conv_mfma_kernel<2><<<dim3(16, 4, B), 256, 0, stream>>>(
        f1, 4, st1, enc1_g, enc1_be, iN1,
        nullptr, 0, nullptr, nullptr, nullptr, 0.f,
        wr2, enc2_b, f2, 4096, 2048, 256, st2);

    // fusion: banded correlation on norm(f2; st2)
    fusion_kernel<<<dim3(64, B), 256, 0, stream>>>(f2, st2, enc2_g, enc2_be, iN2, featn);

    // dec1 (MFMA, stride 1): concat(norm(f1; st1), up2(featn raw)) -> d1 raw + st3
    conv_mfma_kernel<1><<<dim3(32, 2, B), 256, 0, stream>>>(
        f1, 4, st1, enc1_g, enc1_be, iN1,
        featn, 1, nullptr, nullptr, nullptr, 0.f,
        wr3, dec1_b, d1, 4096, 4096, 128, st3);

    // dec0 (MFMA, stride 1): concat(norm(f0; st0), up2(norm(d1; st3))) -> d0 raw + st4
    conv_mfma_kernel<1><<<dim3(64, 2, B), 256, 0, stream>>>(
        f0, 2, st0, enc0_g, enc0_be, iN0,
        d1, 4, st3, dec1_g, dec1_be, iN3,
        wr4, dec0_b, d0, 8192, 8192, 128, st4);

    // flow head (VALU): concat(scan1, up2(norm(d0; st4))) -> flow_r + st5
    flow_kernel<<<dim3(64, 1, B), 256, 0, stream>>>(
        scan1, d0, st4, dec0_g, dec0_be, iN4, flow_w, flow_b, flow_r, st5);

    // final BN + lrelu -> d_out
    final_kernel<<<512, 256, 0, stream>>>(flow_r, st5, flow_g, flow_be, iN5, (float*)d_out);
}